// Round 11
// baseline (12.437 us; speedup 1.0000x reference)
//
#include <hip/hip_runtime.h>

#pragma float_control(precise, on)
#pragma STDC FP_CONTRACT OFF

#define SIGNAL_LENGTH 2048
#define NUM_ITERATIONS 3
#define STEP_SIZE 0.001f
// 10/4/2048 = 5 * 2^-12, exact in f32
#define DERIV_STEP 0.001220703125f
// Reference (XLA) lowers x / 0.00244140625 to x * RN(409.6) — verified
// bit-exact (round 8 absmax = 0.0). DO NOT change to a true divide.
#define RCP_TWO_DERIV_STEP 409.6f

// Opaque value barrier: pins each f32 intermediate in a VGPR so the compiler
// cannot contract/reassociate/re-lower it. NON-volatile: the output is used,
// so it won't be DCE'd, but the scheduler may reorder freely — this restores
// ILP between the independent p1/p2 chains (volatile asms are mutually
// ordered and serialized them in v10).
__device__ __forceinline__ float opq(float x) {
    asm("" : "+v"(x));
    return x;
}

// Select w[o] from a 12-float register window (o in [0,11]).
// All indices compile-time -> pure cndmask tree, no scratch spill.
__device__ __forceinline__ float sel12(const float4& A, const float4& B,
                                       const float4& C, int o) {
    int q = o >> 2;
    int r = o & 3;
    bool q1 = (q == 1), q2 = (q == 2);
    float s0 = q2 ? C.x : (q1 ? B.x : A.x);
    float s1 = q2 ? C.y : (q1 ? B.y : A.y);
    float s2 = q2 ? C.z : (q1 ? B.z : A.z);
    float s3 = q2 ? C.w : (q1 ? B.w : A.w);
    float t0 = (r & 1) ? s1 : s0;
    float t1 = (r & 1) ? s3 : s2;
    return (r & 2) ? t1 : t0;
}

// Linear-interp sample from the register window; arithmetic identical
// (same pinned ops on the same memory values) to the verified v8 path.
__device__ __forceinline__ float sample_win(const float4& A, const float4& B,
                                            const float4& C, int a, float idx) {
#pragma clang fp contract(off)
    int il = (int)floorf(idx);
    il = il < 0 ? 0 : (il > SIGNAL_LENGTH - 1 ? SIGNAL_LENGTH - 1 : il);
    int ir = (int)ceilf(idx);
    ir = ir < 0 ? 0 : (ir > SIGNAL_LENGTH - 1 ? SIGNAL_LENGTH - 1 : ir);
    float w_right = opq(idx - (float)il);
    float w_left  = opq(1.0f - w_right);
    float vl = sel12(A, B, C, il - a);
    float vr = sel12(A, B, C, ir - a);
    float t0 = opq(vl * w_left);
    float t1 = opq(vr * w_right);
    return opq(t0 + t1);
}

// Gradient + curvature sign. 3 sample points span <= 7 consecutive elements;
// fetch with 2 aligned float4 loads + a third loaded ONLY by lanes whose
// span reaches past window float 7 (exec-masked -> inactive lanes generate
// no memory traffic).
__device__ __forceinline__ void gradcurv_v11(const float* __restrict__ row, float pos,
                                             float& g, bool& curv_neg) {
#pragma clang fp contract(off)
    float pos_l = opq(fminf(fmaxf(opq(pos - DERIV_STEP), 0.0f), 1.0f));
    float pos_r = opq(fminf(fmaxf(opq(pos + DERIV_STEP), 0.0f), 1.0f));
    float idxm = opq(pos   * 2047.0f);
    float idxl = opq(pos_l * 2047.0f);
    float idxr = opq(pos_r * 2047.0f);

    // Leftmost needed index: floor(idxl) (pos_l <= pos <= pos_r, monotone).
    int fl = (int)floorf(idxl);
    fl = fl < 0 ? 0 : (fl > SIGNAL_LENGTH - 1 ? SIGNAL_LENGTH - 1 : fl);
    int a = fl & ~3;                       // 16B-aligned window base
    if (a > SIGNAL_LENGTH - 12) a = SIGNAL_LENGTH - 12;  // cover clipped tail

    // Rightmost needed index: ceil(idxr), clipped.
    int cr = (int)ceilf(idxr);
    cr = cr < 0 ? 0 : (cr > SIGNAL_LENGTH - 1 ? SIGNAL_LENGTH - 1 : cr);

    // row is 16B-aligned (8KB row stride), a is a multiple of 4.
    const float4* wp = (const float4*)(row + a);
    float4 A = wp[0];
    float4 B = wp[1];
    float4 C = make_float4(0.0f, 0.0f, 0.0f, 0.0f);
    if (cr - a >= 8) {                     // lane needs window floats 8..11
        C = wp[2];
    }

    float v  = sample_win(A, B, C, a, idxm);
    float vl = sample_win(A, B, C, a, idxl);
    float vr = sample_win(A, B, C, a, idxr);

    float diff = opq(vr - vl);
    g = opq(diff * RCP_TWO_DERIV_STEP);
    float twov = opq(2.0f * v);           // exact (power of 2)
    float num = opq(opq(vr - twov) + vl); // left-to-right
    curv_neg = num < 0.0f;
}

__global__ void grad_refine_v11_kernel(const float* __restrict__ signal,
                                       const float* __restrict__ peaks,
                                       float* __restrict__ out,
                                       int n_rows) {
#pragma clang fp contract(off)
    int tid = blockIdx.x * blockDim.x + threadIdx.x;
    if (tid >= n_rows) return;

    const float* __restrict__ row = signal + (size_t)tid * SIGNAL_LENGTH;
    float p1 = peaks[(size_t)tid * 3 + 0];
    float p2 = peaks[(size_t)tid * 3 + 2];

    #pragma unroll
    for (int it = 0; it < NUM_ITERATIONS; ++it) {
        float g1, g2;
        bool n1, n2;
        gradcurv_v11(row, p1, g1, n1);
        gradcurv_v11(row, p2, g2, n2);
        // a = (-S*g)*mask; mask==1 exact; mask==0 -> +-0 and p+(+-0)==p.
        float a1 = n1 ? opq(-STEP_SIZE * g1) : 0.0f;
        float a2 = n2 ? opq(-STEP_SIZE * g2) : 0.0f;
        p1 = opq(fminf(fmaxf(opq(p1 + a1), 0.0f), 1.0f));
        p2 = opq(fminf(fmaxf(opq(p2 + a2), 0.0f), 1.0f));
    }
    float mid = opq(opq(p1 + p2) * 0.5f);  // /2 == *0.5 exactly

    bool ordered = p1 < p2;
    float o0 = ordered ? p1 : p2;
    float o2 = ordered ? p2 : p1;

    out[(size_t)tid * 3 + 0] = o0;
    out[(size_t)tid * 3 + 1] = mid;
    out[(size_t)tid * 3 + 2] = o2;
}

extern "C" void kernel_launch(void* const* d_in, const int* in_sizes, int n_in,
                              void* d_out, int out_size, void* d_ws, size_t ws_size,
                              hipStream_t stream) {
    // Inputs identified by size: signal = 65536*2048, peaks = 65536*3.
    const float* signal = (const float*)d_in[0];
    const float* peaks  = (const float*)d_in[1];
    if (n_in >= 2 && in_sizes[0] < in_sizes[1]) {
        signal = (const float*)d_in[1];
        peaks  = (const float*)d_in[0];
    }
    float* out = (float*)d_out;

    int n_rows = out_size / 3;
    if (n_rows <= 0) n_rows = 65536;

    int block = 256;
    int grid = (n_rows + block - 1) / block;
    grad_refine_v11_kernel<<<grid, block, 0, stream>>>(signal, peaks, out, n_rows);
}

// Round 12
// 10.645 us; speedup vs baseline: 1.1684x; 1.1684x over previous
//
#include <hip/hip_runtime.h>

#pragma float_control(precise, on)
#pragma STDC FP_CONTRACT OFF

#define SIGNAL_LENGTH 2048
#define NUM_ITERATIONS 3
#define STEP_SIZE 0.001f
// 10/4/2048 = 5 * 2^-12, exact in f32
#define DERIV_STEP 0.001220703125f
// Reference (XLA) lowers x / 0.00244140625 to x * RN(409.6) — verified
// bit-exact (round 8 absmax = 0.0). DO NOT change to a true divide.
#define RCP_TWO_DERIV_STEP 409.6f

// Opaque value barrier: pins each f32 intermediate in a VGPR so the compiler
// cannot contract/reassociate/re-lower it. Non-volatile: may be scheduled
// and CSE'd freely (value-safe), preserving ILP between p1/p2 chains.
__device__ __forceinline__ float opq(float x) {
    asm("" : "+v"(x));
    return x;
}

// Unaligned 16B load (dword-aligned is sufficient on gfx950; lowers to one
// global_load_dwordx4 under the default unaligned-access mode).
__device__ __forceinline__ float4 ld16(const float* __restrict__ p) {
    float4 r;
    __builtin_memcpy(&r, p, sizeof(float4));
    return r;
}

// Select w[o] from an 8-float register window, o in [0,7].
// Compile-time bit tree -> 7 cndmasks, no scratch.
__device__ __forceinline__ float sel8(const float4& W0, const float4& W1, int o) {
    bool hi = (o & 4) != 0;
    float s0 = hi ? W1.x : W0.x;
    float s1 = hi ? W1.y : W0.y;
    float s2 = hi ? W1.z : W0.z;
    float s3 = hi ? W1.w : W0.w;
    float t0 = (o & 1) ? s1 : s0;
    float t1 = (o & 1) ? s3 : s2;
    return (o & 2) ? t1 : t0;
}

// Linear-interp sample from the register window; arithmetic identical
// (same pinned ops on the same memory values) to the verified v8 path.
__device__ __forceinline__ float sample_win(const float4& W0, const float4& W1,
                                            int a, float idx) {
#pragma clang fp contract(off)
    int il = (int)floorf(idx);
    il = il < 0 ? 0 : (il > SIGNAL_LENGTH - 1 ? SIGNAL_LENGTH - 1 : il);
    int ir = (int)ceilf(idx);
    ir = ir < 0 ? 0 : (ir > SIGNAL_LENGTH - 1 ? SIGNAL_LENGTH - 1 : ir);
    float w_right = opq(idx - (float)il);
    float w_left  = opq(1.0f - w_right);
    float vl = sel8(W0, W1, il - a);
    float vr = sel8(W0, W1, ir - a);
    float t0 = opq(vl * w_left);
    float t1 = opq(vr * w_right);
    return opq(t0 + t1);
}

// Gradient + curvature sign. The 3 sample points span [floor(idxl),
// ceil(idxr)] <= 7 consecutive elements; fetch with 2 unaligned 16B loads
// based at floor(idxl) (clamped so offsets stay in [0,7] and loads
// in-bounds). 2 VMEM requests per window instead of v10's 3.
__device__ __forceinline__ void gradcurv_v12(const float* __restrict__ row, float pos,
                                             float& g, bool& curv_neg) {
#pragma clang fp contract(off)
    float pos_l = opq(fminf(fmaxf(opq(pos - DERIV_STEP), 0.0f), 1.0f));
    float pos_r = opq(fminf(fmaxf(opq(pos + DERIV_STEP), 0.0f), 1.0f));
    float idxm = opq(pos   * 2047.0f);
    float idxl = opq(pos_l * 2047.0f);
    float idxr = opq(pos_r * 2047.0f);

    // Window base: clipped floor(idxl), clamped to keep [a, a+7] in-bounds.
    int fl = (int)floorf(idxl);
    fl = fl < 0 ? 0 : (fl > SIGNAL_LENGTH - 1 ? SIGNAL_LENGTH - 1 : fl);
    int a = fl > SIGNAL_LENGTH - 8 ? SIGNAL_LENGTH - 8 : fl;

    float4 W0 = ld16(row + a);
    float4 W1 = ld16(row + a + 4);

    float v  = sample_win(W0, W1, a, idxm);
    float vl = sample_win(W0, W1, a, idxl);
    float vr = sample_win(W0, W1, a, idxr);

    float diff = opq(vr - vl);
    g = opq(diff * RCP_TWO_DERIV_STEP);
    float twov = opq(2.0f * v);           // exact (power of 2)
    float num = opq(opq(vr - twov) + vl); // left-to-right
    curv_neg = num < 0.0f;
}

__global__ void grad_refine_v12_kernel(const float* __restrict__ signal,
                                       const float* __restrict__ peaks,
                                       float* __restrict__ out,
                                       int n_rows) {
#pragma clang fp contract(off)
    int tid = blockIdx.x * blockDim.x + threadIdx.x;
    if (tid >= n_rows) return;

    const float* __restrict__ row = signal + (size_t)tid * SIGNAL_LENGTH;
    float p1 = peaks[(size_t)tid * 3 + 0];
    float p2 = peaks[(size_t)tid * 3 + 2];

    #pragma unroll
    for (int it = 0; it < NUM_ITERATIONS; ++it) {
        float g1, g2;
        bool n1, n2;
        gradcurv_v12(row, p1, g1, n1);
        gradcurv_v12(row, p2, g2, n2);
        // a = (-S*g)*mask; mask==1 exact; mask==0 -> +-0 and p+(+-0)==p.
        float a1 = n1 ? opq(-STEP_SIZE * g1) : 0.0f;
        float a2 = n2 ? opq(-STEP_SIZE * g2) : 0.0f;
        p1 = opq(fminf(fmaxf(opq(p1 + a1), 0.0f), 1.0f));
        p2 = opq(fminf(fmaxf(opq(p2 + a2), 0.0f), 1.0f));
    }
    float mid = opq(opq(p1 + p2) * 0.5f);  // /2 == *0.5 exactly

    bool ordered = p1 < p2;
    float o0 = ordered ? p1 : p2;
    float o2 = ordered ? p2 : p1;

    out[(size_t)tid * 3 + 0] = o0;
    out[(size_t)tid * 3 + 1] = mid;
    out[(size_t)tid * 3 + 2] = o2;
}

extern "C" void kernel_launch(void* const* d_in, const int* in_sizes, int n_in,
                              void* d_out, int out_size, void* d_ws, size_t ws_size,
                              hipStream_t stream) {
    // Inputs identified by size: signal = 65536*2048, peaks = 65536*3.
    const float* signal = (const float*)d_in[0];
    const float* peaks  = (const float*)d_in[1];
    if (n_in >= 2 && in_sizes[0] < in_sizes[1]) {
        signal = (const float*)d_in[1];
        peaks  = (const float*)d_in[0];
    }
    float* out = (float*)d_out;

    int n_rows = out_size / 3;
    if (n_rows <= 0) n_rows = 65536;

    int block = 256;
    int grid = (n_rows + block - 1) / block;
    grad_refine_v12_kernel<<<grid, block, 0, stream>>>(signal, peaks, out, n_rows);
}

// Round 13
// 10.366 us; speedup vs baseline: 1.1998x; 1.0269x over previous
//
#include <hip/hip_runtime.h>

#pragma float_control(precise, on)
#pragma STDC FP_CONTRACT OFF

#define SIGNAL_LENGTH 2048
#define NUM_ITERATIONS 3
#define STEP_SIZE 0.001f
// 10/4/2048 = 5 * 2^-12, exact in f32
#define DERIV_STEP 0.001220703125f
// Reference (XLA) lowers x / 0.00244140625 to x * RN(409.6) — verified
// bit-exact (round 8 absmax = 0.0). DO NOT change to a true divide.
#define RCP_TWO_DERIV_STEP 409.6f

// Opaque value barrier: pins each f32 intermediate in a VGPR so the compiler
// cannot contract/reassociate/re-lower it. Non-volatile (value-safe, free to
// schedule) — preserves ILP between the independent p1/p2 chains.
__device__ __forceinline__ float opq(float x) {
    asm("" : "+v"(x));
    return x;
}

// Unaligned 16B load (dword alignment suffices on gfx950).
__device__ __forceinline__ float4 ld16(const float* __restrict__ p) {
    float4 r;
    __builtin_memcpy(&r, p, sizeof(float4));
    return r;
}

struct f3 { float x, y, z; };

// 12B load/store (lower to global_load/store_dwordx3).
__device__ __forceinline__ f3 ld12(const float* __restrict__ p) {
    f3 r;
    __builtin_memcpy(&r, p, sizeof(f3));
    return r;
}
__device__ __forceinline__ void st12(float* __restrict__ p, f3 v) {
    __builtin_memcpy(p, &v, sizeof(f3));
}

// Select w[o] from an 8-float register window, o in [0,7].
__device__ __forceinline__ float sel8(const float4& W0, const float4& W1, int o) {
    bool hi = (o & 4) != 0;
    float s0 = hi ? W1.x : W0.x;
    float s1 = hi ? W1.y : W0.y;
    float s2 = hi ? W1.z : W0.z;
    float s3 = hi ? W1.w : W0.w;
    float t0 = (o & 1) ? s1 : s0;
    float t1 = (o & 1) ? s3 : s2;
    return (o & 2) ? t1 : t0;
}

// Linear-interp sample from the register window; pinned f32 ops identical to
// the verified bit-exact path.
__device__ __forceinline__ float sample_win(const float4& W0, const float4& W1,
                                            int a, float idx) {
#pragma clang fp contract(off)
    int il = (int)floorf(idx);
    il = il < 0 ? 0 : (il > SIGNAL_LENGTH - 1 ? SIGNAL_LENGTH - 1 : il);
    int ir = (int)ceilf(idx);
    ir = ir < 0 ? 0 : (ir > SIGNAL_LENGTH - 1 ? SIGNAL_LENGTH - 1 : ir);
    float w_right = opq(idx - (float)il);
    float w_left  = opq(1.0f - w_right);
    float vl = sel8(W0, W1, il - a);
    float vr = sel8(W0, W1, ir - a);
    float t0 = opq(vl * w_left);
    float t1 = opq(vr * w_right);
    return opq(t0 + t1);
}

// Gradient + curvature sign. 3 sample points span [floor(idxl), ceil(idxr)]
// <= 7 consecutive elements; fetched as 2 unaligned 16B loads at floor(idxl)
// (clamped in-bounds).
__device__ __forceinline__ void gradcurv_v13(const float* __restrict__ row, float pos,
                                             float& g, bool& curv_neg) {
#pragma clang fp contract(off)
    float pos_l = opq(fminf(fmaxf(opq(pos - DERIV_STEP), 0.0f), 1.0f));
    float pos_r = opq(fminf(fmaxf(opq(pos + DERIV_STEP), 0.0f), 1.0f));
    float idxm = opq(pos   * 2047.0f);
    float idxl = opq(pos_l * 2047.0f);
    float idxr = opq(pos_r * 2047.0f);

    int fl = (int)floorf(idxl);
    fl = fl < 0 ? 0 : (fl > SIGNAL_LENGTH - 1 ? SIGNAL_LENGTH - 1 : fl);
    int a = fl > SIGNAL_LENGTH - 8 ? SIGNAL_LENGTH - 8 : fl;

    float4 W0 = ld16(row + a);
    float4 W1 = ld16(row + a + 4);

    float v  = sample_win(W0, W1, a, idxm);
    float vl = sample_win(W0, W1, a, idxl);
    float vr = sample_win(W0, W1, a, idxr);

    float diff = opq(vr - vl);
    g = opq(diff * RCP_TWO_DERIV_STEP);
    float twov = opq(2.0f * v);           // exact (power of 2)
    float num = opq(opq(vr - twov) + vl); // left-to-right
    curv_neg = num < 0.0f;
}

__global__ void grad_refine_v13_kernel(const float* __restrict__ signal,
                                       const float* __restrict__ peaks,
                                       float* __restrict__ out,
                                       int n_rows) {
#pragma clang fp contract(off)
    int tid = blockIdx.x * blockDim.x + threadIdx.x;
    if (tid >= n_rows) return;

    const float* __restrict__ row = signal + (size_t)tid * SIGNAL_LENGTH;
    // Single 12B load of the row's peak triple (only .x and .z used).
    f3 pk = ld12(peaks + (size_t)tid * 3);
    float p1 = pk.x;
    float p2 = pk.z;

    #pragma unroll
    for (int it = 0; it < NUM_ITERATIONS; ++it) {
        float g1, g2;
        bool n1, n2;
        gradcurv_v13(row, p1, g1, n1);
        gradcurv_v13(row, p2, g2, n2);
        // a = (-S*g)*mask; mask==1 exact; mask==0 -> +-0 and p+(+-0)==p.
        float a1 = n1 ? opq(-STEP_SIZE * g1) : 0.0f;
        float a2 = n2 ? opq(-STEP_SIZE * g2) : 0.0f;
        p1 = opq(fminf(fmaxf(opq(p1 + a1), 0.0f), 1.0f));
        p2 = opq(fminf(fmaxf(opq(p2 + a2), 0.0f), 1.0f));
    }
    float mid = opq(opq(p1 + p2) * 0.5f);  // /2 == *0.5 exactly

    bool ordered = p1 < p2;
    f3 o;
    o.x = ordered ? p1 : p2;
    o.y = mid;
    o.z = ordered ? p2 : p1;
    // Single 12B store of the output triple.
    st12(out + (size_t)tid * 3, o);
}

extern "C" void kernel_launch(void* const* d_in, const int* in_sizes, int n_in,
                              void* d_out, int out_size, void* d_ws, size_t ws_size,
                              hipStream_t stream) {
    // Inputs identified by size: signal = 65536*2048, peaks = 65536*3.
    const float* signal = (const float*)d_in[0];
    const float* peaks  = (const float*)d_in[1];
    if (n_in >= 2 && in_sizes[0] < in_sizes[1]) {
        signal = (const float*)d_in[1];
        peaks  = (const float*)d_in[0];
    }
    float* out = (float*)d_out;

    int n_rows = out_size / 3;
    if (n_rows <= 0) n_rows = 65536;

    int block = 256;
    int grid = (n_rows + block - 1) / block;
    grad_refine_v13_kernel<<<grid, block, 0, stream>>>(signal, peaks, out, n_rows);
}